// Round 2
// baseline (266.188 us; speedup 1.0000x reference)
//
#include <hip/hip_runtime.h>
#include <stdint.h>

#define NCLS 80
#define BGI 80
#define BB 16
#define NGT 32
#define MM 33600
#define EPSF 1e-9f

// IoU exactly mirroring reference pairwise_iou op order; no FMA contraction.
__device__ __forceinline__ float iou_f(const float4 b1, const float4 b2) {
#pragma clang fp contract(off)
  float ltx = fmaxf(b1.x, b2.x);
  float lty = fmaxf(b1.y, b2.y);
  float rbx = fminf(b1.z, b2.z);
  float rby = fminf(b1.w, b2.w);
  float iw = fmaxf(rbx - ltx, 0.0f);
  float ih = fmaxf(rby - lty, 0.0f);
  float inter = iw * ih;
  float a1 = (b1.z - b1.x) * (b1.w - b1.y);
  float a2 = (b2.z - b2.x) * (b2.w - b2.y);
  return inter / (a1 + a2 - inter + EPSF);
}

// K1: one wave per (b,g). Top-9 per level via per-lane sorted insert + 64-lane
// u64-key wave-min merge. Then candidate IoU stats -> threshold -> scatter.
__global__ __launch_bounds__(64) void k_topk(
    const float4* __restrict__ anchors, const float4* __restrict__ gtb,
    const float* __restrict__ maskgt, unsigned int* __restrict__ cnt,
    unsigned int* __restrict__ gidx) {
#pragma clang fp contract(off)
  const int pair = blockIdx.x;            // b*32+g
  if (maskgt[pair] == 0.0f) return;       // masked gt contributes nothing
  const int b = pair >> 5;
  const int g = pair & 31;
  const int lane = threadIdx.x;
  const float4 gb = gtb[pair];
  const float gcx = (gb.x + gb.z) * 0.5f;
  const float gcy = (gb.y + gb.w) * 0.5f;

  unsigned int mycand = 0;  // lane l (<27) owns candidate l
  const int LSTART[3] = {0, 25600, 32000};
  const int LLEN[3]   = {25600, 6400, 1600};

#pragma unroll
  for (int lev = 0; lev < 3; ++lev) {
    float dd[9];
    unsigned int ii[9];
#pragma unroll
    for (int q = 0; q < 9; ++q) { dd[q] = 3.4e38f; ii[q] = 0u; }
    const int start = LSTART[lev];
    const int len = LLEN[lev];
    for (int j = lane; j < len; j += 64) {
      const float4 ab = anchors[start + j];
      const float ax = (ab.x + ab.z) * 0.5f;
      const float ay = (ab.y + ab.w) * 0.5f;
      const float dx = gcx - ax;
      const float dy = gcy - ay;
      const float dist = sqrtf(dx * dx + dy * dy);
      if (dist < dd[8]) {  // strict: keeps earliest index among equals
        float curd = dist;
        unsigned int curi = (unsigned int)(start + j);
#pragma unroll
        for (int q = 0; q < 9; ++q) {  // static-indexed bubble insertion
          const bool less = curd < dd[q];
          const float td = less ? dd[q] : curd;
          const unsigned int ti = less ? ii[q] : curi;
          dd[q] = less ? curd : dd[q];
          ii[q] = less ? curi : ii[q];
          curd = td; curi = ti;
        }
      }
    }
    // merge: 9 pops of global min over (dist,idx) packed keys.
    // Keys are unique across lanes (idx in low bits), so exactly one lane pops.
#pragma unroll
    for (int t = 0; t < 9; ++t) {
      const unsigned long long key =
          ((unsigned long long)__float_as_uint(dd[0]) << 32) |
          (unsigned long long)ii[0];
      unsigned long long mn = key;
#pragma unroll
      for (int s = 32; s >= 1; s >>= 1) {
        const unsigned long long o = __shfl_xor(mn, s, 64);
        mn = (o < mn) ? o : mn;
      }
      if (lane == lev * 9 + t) mycand = (unsigned int)(mn & 0xffffffffu);
      if (key == mn) {
#pragma unroll
        for (int q = 0; q < 8; ++q) { dd[q] = dd[q + 1]; ii[q] = ii[q + 1]; }
        dd[8] = 3.4e38f; ii[8] = 0u;
      }
    }
  }

  // candidate IoUs + inside-gt test
  float ov = 0.0f;
  bool inside = false;
  if (lane < 27) {
    const float4 ab = anchors[mycand];
    ov = iou_f(gb, ab);
    const float ax = (ab.x + ab.z) * 0.5f;
    const float ay = (ab.y + ab.w) * 0.5f;
    const float m1 = fminf(fminf(ax - gb.x, ay - gb.y),
                           fminf(gb.z - ax, gb.w - ay));
    inside = m1 > EPSF;
  }
  // thr = mean + std(ddof=1) over the 27 gathered IoUs
  float s = (lane < 27) ? ov : 0.0f;
#pragma unroll
  for (int sft = 32; sft >= 1; sft >>= 1) s += __shfl_xor(s, sft, 64);
  const float mean = s / 27.0f;
  float dev = (lane < 27) ? (ov - mean) : 0.0f;
  float s2 = dev * dev;
#pragma unroll
  for (int sft = 32; sft >= 1; sft >>= 1) s2 += __shfl_xor(s2, sft, 64);
  const float thr = mean + sqrtf(s2 / 26.0f);

  if (lane < 27 && inside && ov > thr) {
    atomicAdd(&cnt[b * MM + (int)mycand], 1u);
    gidx[b * MM + (int)mycand] = (unsigned int)g;  // only read when cnt==1
  }
}

// B1: per (b,a) final assignment + labels/bboxes/fg outputs + compact record.
__global__ __launch_bounds__(320) void k_assign(
    const float4* __restrict__ anchors, const float4* __restrict__ gtb,
    const int* __restrict__ glabels, const float4* __restrict__ predb,
    const unsigned int* __restrict__ cnt, const unsigned int* __restrict__ gidx,
    float* __restrict__ out_labels, float4* __restrict__ out_bbox,
    float* __restrict__ out_fg, int2* __restrict__ rec) {
  const int a = blockIdx.x * 320 + threadIdx.x;  // 105*320 == 33600 exactly
  const int b = blockIdx.y;
  const int i = b * MM + a;
  const unsigned int c = cnt[i];
  int g = 0;
  const bool fg = (c != 0u);
  if (c == 1u) {
    g = (int)gidx[i];
  } else if (c > 1u) {
    // reference: column replaced by one_hot(argmax_g overlaps) — includes
    // masked gts; first-max tie-break like jnp.argmax.
    const float4 ab = anchors[a];
    float best = -1.0f;
    for (int gg = 0; gg < NGT; ++gg) {
      const float ovv = iou_f(gtb[b * NGT + gg], ab);
      if (ovv > best) { best = ovv; g = gg; }
    }
  }
  const int lbl = fg ? glabels[b * NGT + g] : BGI;
  out_labels[i] = (float)lbl;
  out_bbox[i] = gtb[b * NGT + g];  // !fg -> g==0 (argmax of zeros)
  float io = 0.0f;
  if (fg) io = iou_f(gtb[b * NGT + g], predb[i]);
  out_fg[i] = fg ? 1.0f : 0.0f;
  int2 r;
  r.x = fg ? lbl : -1;
  r.y = __float_as_int(io);
  rec[i] = r;
}

// B2: fully-coalesced float4 writes of the (B,M,80) one-hot*iou score tensor.
__global__ __launch_bounds__(256) void k_scores(
    const int2* __restrict__ rec, float4* __restrict__ out_scores) {
  const int t = blockIdx.x * 256 + threadIdx.x;  // 2625*256 == 672000 == MM*20
  const int b = blockIdx.y;
  const unsigned int row_in = (unsigned int)t / 20u;
  const int k = t - (int)(row_in * 20u);
  const int2 r = rec[b * MM + (int)row_in];
  const float io = __int_as_float(r.y);
  const int base = k * 4;
  float4 v;
  v.x = (r.x == base) ? io : 0.0f;
  v.y = (r.x == base + 1) ? io : 0.0f;
  v.z = (r.x == base + 2) ? io : 0.0f;
  v.w = (r.x == base + 3) ? io : 0.0f;
  out_scores[(size_t)b * 672000 + t] = v;
}

extern "C" void kernel_launch(void* const* d_in, const int* in_sizes, int n_in,
                              void* d_out, int out_size, void* d_ws, size_t ws_size,
                              hipStream_t stream) {
  // Identify inputs by size (robust to how the n_level tuple is passed).
  const float* anchors = nullptr;
  const float* gtb = nullptr;
  const int* glab = nullptr;
  const float* maskgt = nullptr;
  const float* predb = nullptr;
  int seen512 = 0;
  for (int i = 0; i < n_in; ++i) {
    const int sz = in_sizes[i];
    if (sz == 134400 && !anchors) anchors = (const float*)d_in[i];
    else if (sz == 2048 && !gtb) gtb = (const float*)d_in[i];
    else if (sz == 512) {
      if (seen512++ == 0) glab = (const int*)d_in[i];
      else maskgt = (const float*)d_in[i];
    } else if (sz == 2150400 && !predb) predb = (const float*)d_in[i];
  }
  if (!anchors || !gtb || !glab || !maskgt || !predb) return;  // defensive

  float* out = (float*)d_out;
  float* out_labels = out;                          // [B*M]
  float4* out_bbox = (float4*)(out + 537600);       // [B*M][4]
  float4* out_scores = (float4*)(out + 2688000);    // [B*M][80]
  float* out_fg = out + 45696000;                   // [B*M]

  unsigned int* cnt = (unsigned int*)d_ws;          // [B*M]
  unsigned int* gidx = cnt + 537600;                // [B*M]
  int2* rec = (int2*)(gidx + 537600);               // [B*M]

  hipMemsetAsync(cnt, 0, 537600 * sizeof(unsigned int), stream);

  k_topk<<<dim3(BB * NGT), dim3(64), 0, stream>>>(
      (const float4*)anchors, (const float4*)gtb, maskgt, cnt, gidx);

  k_assign<<<dim3(105, BB), dim3(320), 0, stream>>>(
      (const float4*)anchors, (const float4*)gtb, glab, (const float4*)predb,
      cnt, gidx, out_labels, out_bbox, out_fg, rec);

  k_scores<<<dim3(2625, BB), dim3(256), 0, stream>>>(rec, out_scores);
}

// Round 3
// 97.258 us; speedup vs baseline: 2.7369x; 2.7369x over previous
//
#include <hip/hip_runtime.h>
#include <stdint.h>

#define NCLS 80
#define BGI 80
#define BB 16
#define NGT 32
#define MM 33600
#define EPSF 1e-9f
#define INF_KEY 0xffffffffffffffffull

// IoU exactly mirroring reference pairwise_iou op order; no FMA contraction.
__device__ __forceinline__ float iou_f(const float4 b1, const float4 b2) {
#pragma clang fp contract(off)
  float ltx = fmaxf(b1.x, b2.x);
  float lty = fmaxf(b1.y, b2.y);
  float rbx = fminf(b1.z, b2.z);
  float rby = fminf(b1.w, b2.w);
  float iw = fmaxf(rbx - ltx, 0.0f);
  float ih = fmaxf(rby - lty, 0.0f);
  float inter = iw * ih;
  float a1 = (b1.z - b1.x) * (b1.w - b1.y);
  float a2 = (b2.z - b2.x) * (b2.w - b2.y);
  return inter / (a1 + a2 - inter + EPSF);
}

// K1: one 512-thread block (8 waves) per (b,g). Per-lane sorted top-9 over a
// ~67-element strided slice, per-wave 9-pop u64 butterfly merge -> LDS,
// one barrier, wave 0 merges the 8 sorted lists per level (register heads),
// then computes threshold stats and scatters positives.
__global__ __launch_bounds__(512) void k_topk(
    const float4* __restrict__ anchors, const float4* __restrict__ gtb,
    const float* __restrict__ maskgt, unsigned int* __restrict__ cnt,
    unsigned int* __restrict__ gidx) {
#pragma clang fp contract(off)
  const int pair = blockIdx.x;            // b*32+g
  if (maskgt[pair] == 0.0f) return;       // masked gt contributes nothing
  const int b = pair >> 5;
  const int g = pair & 31;
  const int tid = threadIdx.x;
  const int lane = tid & 63;
  const int wid = tid >> 6;
  const float4 gb = gtb[pair];
  const float gcx = (gb.x + gb.z) * 0.5f;
  const float gcy = (gb.y + gb.w) * 0.5f;

  __shared__ unsigned long long smem[3][8][9];  // per-level per-wave sorted top9

  const int LSTART[3] = {0, 25600, 32000};
  const int LLEN[3]   = {25600, 6400, 1600};

#pragma unroll
  for (int lev = 0; lev < 3; ++lev) {
    float dd[9];
    unsigned int ii[9];
#pragma unroll
    for (int q = 0; q < 9; ++q) { dd[q] = 3.4e38f; ii[q] = 0u; }
    const int start = LSTART[lev];
    const int len = LLEN[lev];
    for (int j = tid; j < len; j += 512) {
      const float4 ab = anchors[start + j];
      const float ax = (ab.x + ab.z) * 0.5f;
      const float ay = (ab.y + ab.w) * 0.5f;
      const float dx = gcx - ax;
      const float dy = gcy - ay;
      const float dist = sqrtf(dx * dx + dy * dy);
      if (dist < dd[8]) {  // strict: keeps earliest index among equals
        float curd = dist;
        unsigned int curi = (unsigned int)(start + j);
#pragma unroll
        for (int q = 0; q < 9; ++q) {  // static-indexed bubble insertion
          const bool less = curd < dd[q];
          const float td = less ? dd[q] : curd;
          const unsigned int ti = less ? ii[q] : curi;
          dd[q] = less ? curd : dd[q];
          ii[q] = less ? curi : ii[q];
          curd = td; curi = ti;
        }
      }
    }
    // per-wave merge: 9 pops of 64-lane min over packed (dist,idx) keys.
    // Keys unique (idx in low bits) -> exactly one lane pops per step.
#pragma unroll
    for (int t = 0; t < 9; ++t) {
      const unsigned long long key =
          ((unsigned long long)__float_as_uint(dd[0]) << 32) |
          (unsigned long long)ii[0];
      unsigned long long mn = key;
#pragma unroll
      for (int s = 32; s >= 1; s >>= 1) {
        const unsigned long long o = __shfl_xor(mn, s, 64);
        mn = (o < mn) ? o : mn;
      }
      if (lane == 0) smem[lev][wid][t] = mn;
      if (key == mn) {
#pragma unroll
        for (int q = 0; q < 8; ++q) { dd[q] = dd[q + 1]; ii[q] = ii[q + 1]; }
        dd[8] = 3.4e38f; ii[8] = 0u;
      }
    }
  }

  __syncthreads();
  if (wid != 0) return;  // only wave 0 continues (no more barriers)

  // wave 0: merge 8 sorted lists of 9 per level; candidate (lev*9+t) -> lane.
  unsigned int mycand = 0;
#pragma unroll
  for (int lev = 0; lev < 3; ++lev) {
    unsigned long long lst[9];
#pragma unroll
    for (int q = 0; q < 9; ++q)
      lst[q] = (lane < 8) ? smem[lev][lane][q] : INF_KEY;
#pragma unroll
    for (int t = 0; t < 9; ++t) {
      unsigned long long mn = lst[0];
#pragma unroll
      for (int s = 4; s >= 1; s >>= 1) {  // butterfly over 8-lane group
        const unsigned long long o = __shfl_xor(mn, s, 64);
        mn = (o < mn) ? o : mn;
      }
      const unsigned long long mnb = __shfl(mn, 0, 64);  // broadcast to all
      if (lane == lev * 9 + t) mycand = (unsigned int)(mnb & 0xffffffffu);
      if (lst[0] == mnb) {  // winner advances its list
#pragma unroll
        for (int q = 0; q < 8; ++q) lst[q] = lst[q + 1];
        lst[8] = INF_KEY;
      }
    }
  }

  // candidate IoUs + inside-gt test (lanes 0..26)
  float ov = 0.0f;
  bool inside = false;
  if (lane < 27) {
    const float4 ab = anchors[mycand];
    ov = iou_f(gb, ab);
    const float ax = (ab.x + ab.z) * 0.5f;
    const float ay = (ab.y + ab.w) * 0.5f;
    const float m1 = fminf(fminf(ax - gb.x, ay - gb.y),
                           fminf(gb.z - ax, gb.w - ay));
    inside = m1 > EPSF;
  }
  // thr = mean + std(ddof=1) over the 27 gathered IoUs
  float s = (lane < 27) ? ov : 0.0f;
#pragma unroll
  for (int sft = 32; sft >= 1; sft >>= 1) s += __shfl_xor(s, sft, 64);
  const float mean = s / 27.0f;
  float dev = (lane < 27) ? (ov - mean) : 0.0f;
  float s2 = dev * dev;
#pragma unroll
  for (int sft = 32; sft >= 1; sft >>= 1) s2 += __shfl_xor(s2, sft, 64);
  const float thr = mean + sqrtf(s2 / 26.0f);

  if (lane < 27 && inside && ov > thr) {
    atomicAdd(&cnt[b * MM + (int)mycand], 1u);
    gidx[b * MM + (int)mycand] = (unsigned int)g;  // only read when cnt==1
  }
}

// B1: per (b,a) final assignment + labels/bboxes/fg outputs + compact record.
__global__ __launch_bounds__(320) void k_assign(
    const float4* __restrict__ anchors, const float4* __restrict__ gtb,
    const int* __restrict__ glabels, const float4* __restrict__ predb,
    const unsigned int* __restrict__ cnt, const unsigned int* __restrict__ gidx,
    float* __restrict__ out_labels, float4* __restrict__ out_bbox,
    float* __restrict__ out_fg, int2* __restrict__ rec) {
  const int a = blockIdx.x * 320 + threadIdx.x;  // 105*320 == 33600 exactly
  const int b = blockIdx.y;
  const int i = b * MM + a;
  const unsigned int c = cnt[i];
  int g = 0;
  const bool fg = (c != 0u);
  if (c == 1u) {
    g = (int)gidx[i];
  } else if (c > 1u) {
    // reference: column replaced by one_hot(argmax_g overlaps) — includes
    // masked gts; first-max tie-break like jnp.argmax.
    const float4 ab = anchors[a];
    float best = -1.0f;
    for (int gg = 0; gg < NGT; ++gg) {
      const float ovv = iou_f(gtb[b * NGT + gg], ab);
      if (ovv > best) { best = ovv; g = gg; }
    }
  }
  const int lbl = fg ? glabels[b * NGT + g] : BGI;
  out_labels[i] = (float)lbl;
  out_bbox[i] = gtb[b * NGT + g];  // !fg -> g==0 (argmax of zeros)
  float io = 0.0f;
  if (fg) io = iou_f(gtb[b * NGT + g], predb[i]);
  out_fg[i] = fg ? 1.0f : 0.0f;
  int2 r;
  r.x = fg ? lbl : -1;
  r.y = __float_as_int(io);
  rec[i] = r;
}

// B2: fully-coalesced float4 writes of the (B,M,80) one-hot*iou score tensor.
__global__ __launch_bounds__(256) void k_scores(
    const int2* __restrict__ rec, float4* __restrict__ out_scores) {
  const int t = blockIdx.x * 256 + threadIdx.x;  // 2625*256 == 672000 == MM*20
  const int b = blockIdx.y;
  const unsigned int row_in = (unsigned int)t / 20u;
  const int k = t - (int)(row_in * 20u);
  const int2 r = rec[b * MM + (int)row_in];
  const float io = __int_as_float(r.y);
  const int base = k * 4;
  float4 v;
  v.x = (r.x == base) ? io : 0.0f;
  v.y = (r.x == base + 1) ? io : 0.0f;
  v.z = (r.x == base + 2) ? io : 0.0f;
  v.w = (r.x == base + 3) ? io : 0.0f;
  out_scores[(size_t)b * 672000 + t] = v;
}

extern "C" void kernel_launch(void* const* d_in, const int* in_sizes, int n_in,
                              void* d_out, int out_size, void* d_ws, size_t ws_size,
                              hipStream_t stream) {
  // Identify inputs by size (robust to how the n_level tuple is passed).
  const float* anchors = nullptr;
  const float* gtb = nullptr;
  const int* glab = nullptr;
  const float* maskgt = nullptr;
  const float* predb = nullptr;
  int seen512 = 0;
  for (int i = 0; i < n_in; ++i) {
    const int sz = in_sizes[i];
    if (sz == 134400 && !anchors) anchors = (const float*)d_in[i];
    else if (sz == 2048 && !gtb) gtb = (const float*)d_in[i];
    else if (sz == 512) {
      if (seen512++ == 0) glab = (const int*)d_in[i];
      else maskgt = (const float*)d_in[i];
    } else if (sz == 2150400 && !predb) predb = (const float*)d_in[i];
  }
  if (!anchors || !gtb || !glab || !maskgt || !predb) return;  // defensive

  float* out = (float*)d_out;
  float* out_labels = out;                          // [B*M]
  float4* out_bbox = (float4*)(out + 537600);       // [B*M][4]
  float4* out_scores = (float4*)(out + 2688000);    // [B*M][80]
  float* out_fg = out + 45696000;                   // [B*M]

  unsigned int* cnt = (unsigned int*)d_ws;          // [B*M]
  unsigned int* gidx = cnt + 537600;                // [B*M]
  int2* rec = (int2*)(gidx + 537600);               // [B*M]

  hipMemsetAsync(cnt, 0, 537600 * sizeof(unsigned int), stream);

  k_topk<<<dim3(BB * NGT), dim3(512), 0, stream>>>(
      (const float4*)anchors, (const float4*)gtb, maskgt, cnt, gidx);

  k_assign<<<dim3(105, BB), dim3(320), 0, stream>>>(
      (const float4*)anchors, (const float4*)gtb, glab, (const float4*)predb,
      cnt, gidx, out_labels, out_bbox, out_fg, rec);

  k_scores<<<dim3(2625, BB), dim3(256), 0, stream>>>(rec, out_scores);
}